// Round 1
// baseline (155.842 us; speedup 1.0000x reference)
//
#include <hip/hip_runtime.h>

#define BS        64
#define HSTRIDE   1862          // max dim; stride for all h buffers and acc
#define W_TOTAL_C 2234368
#define B_TOTAL_C 3526

// ---------------------------------------------------------------------------
// zero the accumulator (64 x 1862 f32) — vectorized
__global__ void zero_acc_kernel(float4* __restrict__ p, int n4) {
    int i = blockIdx.x * blockDim.x + threadIdx.x;
    if (i < n4) p[i] = make_float4(0.f, 0.f, 0.f, 0.f);
}

// ---------------------------------------------------------------------------
// partial batched matvec: acc[b][o] += sum_{i in k-chunk} h[b][i] * W[b][i][o]
// W[b][i][o] = wbase[b*W_TOTAL + w_off + i*dout + o]
template<int VEC>
__global__ void matvec_partial(const float* __restrict__ hin,
                               const float* __restrict__ wbase,
                               float* __restrict__ acc,
                               int din, int dout, int w_off, int kc)
{
    const int b  = blockIdx.z;
    const int k0 = blockIdx.y * kc;
    const int rem = din - k0;
    const int n  = rem < kc ? rem : kc;

    extern __shared__ float sh[];
    for (int i = threadIdx.x; i < n; i += blockDim.x)
        sh[i] = hin[b * HSTRIDE + k0 + i];
    __syncthreads();

    const int o = (blockIdx.x * blockDim.x + threadIdx.x) * VEC;
    if (o >= dout) return;

    const float* wp = wbase + (size_t)b * W_TOTAL_C + w_off
                            + (size_t)k0 * dout + o;

    float a0 = 0.f, a1 = 0.f, a2 = 0.f, a3 = 0.f;
    if (VEC == 4) {
        #pragma unroll 4
        for (int i = 0; i < n; ++i) {
            const float hv = sh[i];
            const float4 w = *reinterpret_cast<const float4*>(wp);
            a0 = fmaf(hv, w.x, a0);
            a1 = fmaf(hv, w.y, a1);
            a2 = fmaf(hv, w.z, a2);
            a3 = fmaf(hv, w.w, a3);
            wp += dout;
        }
    } else {
        #pragma unroll 4
        for (int i = 0; i < n; ++i) {
            const float hv = sh[i];
            const float2 w = *reinterpret_cast<const float2*>(wp);
            a0 = fmaf(hv, w.x, a0);
            a1 = fmaf(hv, w.y, a1);
            wp += dout;
        }
    }

    float* ap = acc + b * HSTRIDE + o;
    atomicAdd(ap + 0, a0);
    atomicAdd(ap + 1, a1);
    if (VEC == 4) {
        atomicAdd(ap + 2, a2);
        atomicAdd(ap + 3, a3);
    }
}

// ---------------------------------------------------------------------------
// epilogue: h_out = act(acc + bias); re-zero acc cells for reuse by later layers
template<int ACT>   // 0 = silu, 1 = tanh
__global__ void epilogue_kernel(float* __restrict__ acc,
                                const float* __restrict__ bias,
                                float* __restrict__ hout,
                                int dout, int b_off)
{
    const int b = blockIdx.y;
    const int o = blockIdx.x * blockDim.x + threadIdx.x;
    if (o >= dout) return;
    const int ai = b * HSTRIDE + o;
    float v = acc[ai] + bias[b * B_TOTAL_C + b_off + o];
    acc[ai] = 0.f;
    float r;
    if (ACT == 0) r = v / (1.f + __expf(-v));   // silu
    else          r = tanhf(v);
    hout[b * HSTRIDE + o] = r;
}

// ---------------------------------------------------------------------------
extern "C" void kernel_launch(void* const* d_in, const int* in_sizes, int n_in,
                              void* d_out, int out_size, void* d_ws, size_t ws_size,
                              hipStream_t stream)
{
    const float* x    = (const float*)d_in[0];   // [64][1862]
    const float* wts  = (const float*)d_in[1];   // [64][W_TOTAL]
    const float* bias = (const float*)d_in[2];   // [64][B_TOTAL]
    float* out = (float*)d_out;                  // [64][1862]

    float* acc = (float*)d_ws;                   // [64][HSTRIDE]
    float* hA  = acc + BS * HSTRIDE;             // [64][HSTRIDE]
    float* hB  = hA  + BS * HSTRIDE;             // [64][HSTRIDE]

    // zero acc (covers first use of every region; epilogues re-zero after read)
    {
        const int n4 = BS * HSTRIDE / 4;
        zero_acc_kernel<<<(n4 + 255) / 256, 256, 0, stream>>>((float4*)acc, n4);
    }

    struct LayerCfg { int din, dout, w_off, b_off, vec, blk, kc; };
    const LayerCfg L[6] = {
        { 1862,  512,       0,    0, 4, 128, 128 },   // L0
        {  512,  256,  953344,  512, 4,  64,  32 },   // L1
        {  256,  128, 1084416,  768, 2,  64,  32 },   // L2
        {  128,  256, 1117184,  896, 4,  64,  16 },   // L3
        {  256,  512, 1149952, 1152, 4, 128,  32 },   // L4
        {  512, 1862, 1281024, 1664, 2, 256, 128 },   // L5
    };

    const float* hin = x;
    float* houts[6] = { hA, hB, hA, hB, hA, out };

    for (int i = 0; i < 6; ++i) {
        const LayerCfg& c = L[i];
        const int noc = (c.dout + c.blk * c.vec - 1) / (c.blk * c.vec);
        const int nk  = (c.din + c.kc - 1) / c.kc;
        dim3 grid(noc, nk, BS), block(c.blk);
        const size_t shmem = (size_t)c.kc * sizeof(float);
        if (c.vec == 4)
            matvec_partial<4><<<grid, block, shmem, stream>>>(
                hin, wts, acc, c.din, c.dout, c.w_off, c.kc);
        else
            matvec_partial<2><<<grid, block, shmem, stream>>>(
                hin, wts, acc, c.din, c.dout, c.w_off, c.kc);

        dim3 egrid((c.dout + 255) / 256, BS), eblock(256);
        if (i < 5)
            epilogue_kernel<0><<<egrid, eblock, 0, stream>>>(
                acc, bias, houts[i], c.dout, c.b_off);
        else
            epilogue_kernel<1><<<egrid, eblock, 0, stream>>>(
                acc, bias, houts[i], c.dout, c.b_off);

        hin = houts[i];
    }
}